// Round 4
// baseline (315.061 us; speedup 1.0000x reference)
//
#include <hip/hip_runtime.h>

#define NDIM 32
#define EDIM 16
#define NHID 64
#define NIN1 144
#define SCHUNK 1024  // counts per scan block
#define SPT 4        // counts per thread (256 threads/block)

// ---------------------------------------------------------------------------
// 1) Histogram of dst -> counts[N]
// ---------------------------------------------------------------------------
__global__ __launch_bounds__(256) void sse_hist(
    const int* __restrict__ dst, int* __restrict__ counts, int E) {
  int e = blockIdx.x * 256 + threadIdx.x;
  if (e < E) atomicAdd(&counts[dst[e]], 1);
}

// ---------------------------------------------------------------------------
// 2a) Per-block partial sums over 1024-count chunks.
// ---------------------------------------------------------------------------
__global__ __launch_bounds__(256) void sse_scan_part(
    const int* __restrict__ counts, int* __restrict__ bsum, int N) {
  __shared__ int ws[4];
  int t = threadIdx.x;
  int base = blockIdx.x * SCHUNK + t * SPT;
  int s = 0;
#pragma unroll
  for (int i = 0; i < SPT; ++i) {
    int idx = base + i;
    if (idx < N) s += counts[idx];
  }
  int v = s;
#pragma unroll
  for (int off = 1; off < 64; off <<= 1) v += __shfl_xor(v, off, 64);
  if ((t & 63) == 0) ws[t >> 6] = v;
  __syncthreads();
  if (t == 0) bsum[blockIdx.x] = ws[0] + ws[1] + ws[2] + ws[3];
}

// ---------------------------------------------------------------------------
// 2b) Final scan (merged top-level): each block scalarly sums bsum[j<blk]
//     (<=48 uniform loads), re-scans its chunk, emits starts & cursors.
//     Last block also writes starts[N] = E.
// ---------------------------------------------------------------------------
__global__ __launch_bounds__(256) void sse_scan_final(
    const int* __restrict__ counts, const int* __restrict__ bsum,
    int* __restrict__ starts, int* __restrict__ cursors, int N, int nb) {
  __shared__ int ws[4];
  int t = threadIdx.x;
  int lane = t & 63, w = t >> 6;
  int boff = 0;
  for (int j = 0; j < (int)blockIdx.x; ++j) boff += bsum[j];
  int base = blockIdx.x * SCHUNK + t * SPT;
  int c[SPT];
  int s = 0;
#pragma unroll
  for (int i = 0; i < SPT; ++i) {
    int idx = base + i;
    c[i] = (idx < N) ? counts[idx] : 0;
    s += c[i];
  }
  int incl = s;
#pragma unroll
  for (int off = 1; off < 64; off <<= 1) {
    int u = __shfl_up(incl, off, 64);
    if (lane >= off) incl += u;
  }
  if (lane == 63) ws[w] = incl;
  __syncthreads();
  int woff = 0;
#pragma unroll
  for (int j = 0; j < 4; ++j)
    if (j < w) woff += ws[j];
  int run = boff + woff + (incl - s);
#pragma unroll
  for (int i = 0; i < SPT; ++i) {
    int idx = base + i;
    if (idx < N) {
      starts[idx] = run;
      cursors[idx] = run;
      run += c[i];
    }
  }
  if ((int)blockIdx.x == nb - 1 && t == 0)
    starts[N] = boff + ws[0] + ws[1] + ws[2] + ws[3];
}

// ---------------------------------------------------------------------------
// 3) Build sorted edge lists: place (src, eid) at cursor[dst]++
// ---------------------------------------------------------------------------
__global__ __launch_bounds__(256) void sse_build(
    const int* __restrict__ src, const int* __restrict__ dst,
    int* __restrict__ cursors, int* __restrict__ ssrc,
    int* __restrict__ seid, int E) {
  int e = blockIdx.x * 256 + threadIdx.x;
  if (e >= E) return;
  int d = dst[e];
  int pos = atomicAdd(&cursors[d], 1);
  ssrc[pos] = src[e];
  seid[pos] = e;
}

// ---------------------------------------------------------------------------
// 4) Atomic-free gather: one wave per node walks its edge range (unroll 8
//    for more outstanding 256B row fetches).
// ---------------------------------------------------------------------------
__global__ __launch_bounds__(256) void sse_gather(
    const float* __restrict__ h, const float* __restrict__ ef,
    const int* __restrict__ starts, const int* __restrict__ ssrc,
    const int* __restrict__ seid, float* __restrict__ efsum,
    float* __restrict__ hsum, int N) {
  int node = blockIdx.x * 4 + (threadIdx.x >> 6);
  int lane = threadIdx.x & 63;
  if (node >= N) return;
  int st = starts[node], en = starts[node + 1];
  float hs = 0.f, es = 0.f;
  int j = st;
  for (; j + 7 < en; j += 8) {
    float a0 = h[ssrc[j + 0] * NHID + lane], a1 = h[ssrc[j + 1] * NHID + lane];
    float a2 = h[ssrc[j + 2] * NHID + lane], a3 = h[ssrc[j + 3] * NHID + lane];
    float a4 = h[ssrc[j + 4] * NHID + lane], a5 = h[ssrc[j + 5] * NHID + lane];
    float a6 = h[ssrc[j + 6] * NHID + lane], a7 = h[ssrc[j + 7] * NHID + lane];
    hs += ((a0 + a1) + (a2 + a3)) + ((a4 + a5) + (a6 + a7));
    if (lane < EDIM) {
      float b0 = ef[seid[j + 0] * EDIM + lane], b1 = ef[seid[j + 1] * EDIM + lane];
      float b2 = ef[seid[j + 2] * EDIM + lane], b3 = ef[seid[j + 3] * EDIM + lane];
      float b4 = ef[seid[j + 4] * EDIM + lane], b5 = ef[seid[j + 5] * EDIM + lane];
      float b6 = ef[seid[j + 6] * EDIM + lane], b7 = ef[seid[j + 7] * EDIM + lane];
      es += ((b0 + b1) + (b2 + b3)) + ((b4 + b5) + (b6 + b7));
    }
  }
  for (; j < en; ++j) {
    hs += h[ssrc[j] * NHID + lane];
    if (lane < EDIM) es += ef[seid[j] * EDIM + lane];
  }
  hsum[node * NHID + lane] = hs;
  if (lane < EDIM) efsum[node * EDIM + lane] = es;
}

// ---------------------------------------------------------------------------
// 5) Node MLP, lane = node. Wave handles 32 nodes; lanes 0-31 compute output
//    rows r in [0,32), lanes 32-63 (same nodes) rows [32,64).
//    z is read per-lane from each node's own rows via float4 global loads
//    (L1-resident); weights are half-uniform LDS broadcasts (2 distinct
//    addresses/wave = conflict-free). Layer-2 gets the other half's relu'd
//    activations via __shfl_xor(32). VALU-bound by design (~6.7k FMA/wave).
// ---------------------------------------------------------------------------
__global__ __launch_bounds__(256) void sse_node(
    const float* __restrict__ h, const float* __restrict__ nf,
    const float* __restrict__ efsum, const float* __restrict__ hsum,
    const int* __restrict__ starts, const float* __restrict__ W1,
    const float* __restrict__ W2, float* __restrict__ out, int N) {
  __shared__ float4 w1v[NHID][NIN1 / 4];  // [64][36] = 36 KB, w1v[r][k4]
  __shared__ float4 w2v[NHID][NHID / 4];  // [64][16] = 16 KB

  int tid = threadIdx.x;
  // flat float4 copy: LDS row-major [r][k4] == W row-major float4 view
  for (int i = tid; i < NHID * (NIN1 / 4); i += 256)
    ((float4*)w1v)[i] = ((const float4*)W1)[i];
  for (int i = tid; i < NHID * (NHID / 4); i += 256)
    ((float4*)w2v)[i] = ((const float4*)W2)[i];
  __syncthreads();

  int lane = tid & 63;
  int hf = lane >> 5;               // output-row half
  int w = tid >> 6;                 // wave id
  int node = blockIdx.x * 128 + w * 32 + (lane & 31);
  int nodeC = node < N ? node : N - 1;

  int st = starts[nodeC], en = starts[nodeC + 1];
  float dg = (float)(en - st);

  const float4* nfr = (const float4*)(nf + (size_t)nodeC * NDIM);     // 8
  const float4* efr = (const float4*)(efsum + (size_t)nodeC * EDIM);  // 4
  const float4* hsr = (const float4*)(hsum + (size_t)nodeC * NHID);   // 16

  float acc[32];
#pragma unroll
  for (int j = 0; j < 32; ++j) acc[j] = 0.f;

  // ---- layer 1 ----
  // k in [0,32): nf ; k in [32,64): dg*nf
  for (int k4 = 0; k4 < 8; ++k4) {
    float4 v = nfr[k4];
    float4 vd = make_float4(dg * v.x, dg * v.y, dg * v.z, dg * v.w);
#pragma unroll
    for (int j = 0; j < 32; ++j) {
      float4 wa = w1v[hf * 32 + j][k4];
      float4 wb = w1v[hf * 32 + j][k4 + 8];
      float t0 = fmaf(wa.x, v.x, acc[j]);
      t0 = fmaf(wa.y, v.y, t0);
      t0 = fmaf(wa.z, v.z, t0);
      t0 = fmaf(wa.w, v.w, t0);
      t0 = fmaf(wb.x, vd.x, t0);
      t0 = fmaf(wb.y, vd.y, t0);
      t0 = fmaf(wb.z, vd.z, t0);
      acc[j] = fmaf(wb.w, vd.w, t0);
    }
  }
  // k in [64,80): efsum
  for (int k4 = 0; k4 < 4; ++k4) {
    float4 v = efr[k4];
#pragma unroll
    for (int j = 0; j < 32; ++j) {
      float4 wa = w1v[hf * 32 + j][16 + k4];
      float t0 = fmaf(wa.x, v.x, acc[j]);
      t0 = fmaf(wa.y, v.y, t0);
      t0 = fmaf(wa.z, v.z, t0);
      acc[j] = fmaf(wa.w, v.w, t0);
    }
  }
  // k in [80,144): hsum
  for (int k4 = 0; k4 < 16; ++k4) {
    float4 v = hsr[k4];
#pragma unroll
    for (int j = 0; j < 32; ++j) {
      float4 wa = w1v[hf * 32 + j][20 + k4];
      float t0 = fmaf(wa.x, v.x, acc[j]);
      t0 = fmaf(wa.y, v.y, t0);
      t0 = fmaf(wa.z, v.z, t0);
      acc[j] = fmaf(wa.w, v.w, t0);
    }
  }

  // relu + cross-half exchange
  float oth[32];
#pragma unroll
  for (int j = 0; j < 32; ++j) {
    acc[j] = fmaxf(acc[j], 0.0f);
    oth[j] = __shfl_xor(acc[j], 32, 64);
  }

  // ---- layer 2 ---- o[j] for r2 = hf*32 + j, summing all 64 r
  float o[32];
#pragma unroll
  for (int j = 0; j < 32; ++j) {
    int r2 = hf * 32 + j;
    float s0 = 0.f, s1 = 0.f;
#pragma unroll
    for (int k4 = 0; k4 < 8; ++k4) {
      float4 wo = w2v[r2][hf * 8 + k4];        // weights for my-half r's
      float4 wx = w2v[r2][(hf ^ 1) * 8 + k4];  // weights for other-half r's
      s0 = fmaf(wo.x, acc[k4 * 4 + 0], s0);
      s0 = fmaf(wo.y, acc[k4 * 4 + 1], s0);
      s0 = fmaf(wo.z, acc[k4 * 4 + 2], s0);
      s0 = fmaf(wo.w, acc[k4 * 4 + 3], s0);
      s1 = fmaf(wx.x, oth[k4 * 4 + 0], s1);
      s1 = fmaf(wx.y, oth[k4 * 4 + 1], s1);
      s1 = fmaf(wx.z, oth[k4 * 4 + 2], s1);
      s1 = fmaf(wx.w, oth[k4 * 4 + 3], s1);
    }
    o[j] = s0 + s1;
  }

  // ---- store (float4; passthrough h where deg==0) ----
  if (node < N) {
    float4* orow = (float4*)(out + (size_t)node * NHID + hf * 32);
    if (dg == 0.0f) {
      const float4* hrow = (const float4*)(h + (size_t)node * NHID + hf * 32);
#pragma unroll
      for (int j4 = 0; j4 < 8; ++j4) orow[j4] = hrow[j4];
    } else {
#pragma unroll
      for (int j4 = 0; j4 < 8; ++j4)
        orow[j4] = make_float4(o[j4 * 4 + 0], o[j4 * 4 + 1],
                               o[j4 * 4 + 2], o[j4 * 4 + 3]);
    }
  }
}

extern "C" void kernel_launch(void* const* d_in, const int* in_sizes, int n_in,
                              void* d_out, int out_size, void* d_ws, size_t ws_size,
                              hipStream_t stream) {
  const float* h  = (const float*)d_in[0];
  const float* nf = (const float*)d_in[1];
  const float* ef = (const float*)d_in[2];
  const int*   src = (const int*)d_in[3];
  const int*   dst = (const int*)d_in[4];
  const float* W1 = (const float*)d_in[5];
  const float* W2 = (const float*)d_in[6];
  float* out = (float*)d_out;

  int N = in_sizes[0] / NHID;  // h is [N, 64]
  int E = in_sizes[3];         // src is [E]

  // ws layout (4-byte elems):
  // counts[N] | starts[N+1] | cursors[N] | bsum[64] |
  // ssrc[E] | seid[E] | efsum[N*16] | hsum[N*64]
  int* counts  = (int*)d_ws;
  int* starts  = counts + N;
  int* cursors = starts + N + 1;
  int* bsum    = cursors + N;
  int* ssrc    = bsum + 64;
  int* seid    = ssrc + E;
  float* efsum = (float*)(seid + E);
  float* hsum  = efsum + (size_t)N * EDIM;

  hipMemsetAsync(counts, 0, (size_t)N * sizeof(int), stream);

  int eblocks = (E + 255) / 256;
  int nb = (N + SCHUNK - 1) / SCHUNK;  // 49 for N=50000 (<= 64)

  sse_hist<<<eblocks, 256, 0, stream>>>(dst, counts, E);
  sse_scan_part<<<nb, 256, 0, stream>>>(counts, bsum, N);
  sse_scan_final<<<nb, 256, 0, stream>>>(counts, bsum, starts, cursors, N, nb);
  sse_build<<<eblocks, 256, 0, stream>>>(src, dst, cursors, ssrc, seid, E);

  int gblocks = (N + 3) / 4;
  sse_gather<<<gblocks, 256, 0, stream>>>(h, ef, starts, ssrc, seid,
                                          efsum, hsum, N);

  int nchunks = (N + 127) / 128;  // 391 blocks, 32 nodes/wave
  sse_node<<<nchunks, 256, 0, stream>>>(h, nf, efsum, hsum, starts, W1, W2,
                                        out, N);
}